// Round 1
// baseline (14.471 us; speedup 1.0000x reference)
//
#include <hip/hip_runtime.h>

// The entire reference network collapses:
//   weight = softmax(..., axis=-2)  normalizes over j, and
//   out[i,k] = sum_j weight[i,j,k] * value[i,k] = value[i,k] * 1
// so out = feat @ Wv.T + bv. Single small GEMM, memory/launch-bound.

#define NROWS 2048
#define DIM 128

__global__ __launch_bounds__(256) void value_gemm_kernel(
    const float* __restrict__ feat,   // [2048,128]
    const float* __restrict__ Wv,     // [128,128] (out = feat @ Wv^T)
    const float* __restrict__ bv,     // [128]
    float* __restrict__ out)          // [2048,128]
{
    // Wv staged row-major [k][d] as float4 granules, XOR-swizzled:
    // granule (d/4) stored at (d/4) ^ (k & 31). Exactly 64 KiB.
    __shared__ float wlds[DIM * DIM];

    const int t = threadIdx.x;
    const float4* wv4 = (const float4*)Wv;
    float4* wl4 = (float4*)wlds;

    // Stage: 4096 float4s, 16 per thread. m -> k = m/32, d4 = m%32.
    // Writes are conflict-free under the swizzle (lanes hit distinct granules).
#pragma unroll
    for (int i = 0; i < 16; ++i) {
        int m = t + i * 256;
        int k = m >> 5;
        int d4 = m & 31;
        wl4[(k << 5) | (d4 ^ (k & 31))] = wv4[m];
    }
    __syncthreads();

    const int k  = t & 127;                 // output column
    const int ty = t >> 7;                  // 0..1
    const int row0 = blockIdx.x * 16 + ty * 8;   // 8 rows per thread

    float acc[8];
    const float bk = bv[k];
#pragma unroll
    for (int j = 0; j < 8; ++j) acc[j] = bk;

    const float4* f4 = (const float4*)(feat + row0 * DIM);

    // Dot products over d, 4 at a time. LDS read is 2-way conflict (free);
    // feat reads are wave-uniform float4 (single transaction, L1-hot).
#pragma unroll 4
    for (int d4 = 0; d4 < 32; ++d4) {
        float4 w = wl4[(k << 5) | (d4 ^ (k & 31))];
#pragma unroll
        for (int j = 0; j < 8; ++j) {
            float4 f = f4[j * 32 + d4];
            acc[j] += f.x * w.x + f.y * w.y + f.z * w.z + f.w * w.w;
        }
    }

#pragma unroll
    for (int j = 0; j < 8; ++j) {
        out[(row0 + j) * DIM + k] = acc[j];
    }
}

extern "C" void kernel_launch(void* const* d_in, const int* in_sizes, int n_in,
                              void* d_out, int out_size, void* d_ws, size_t ws_size,
                              hipStream_t stream) {
    // setup_inputs order: 0 feat, 1 bias, 2 mul, 3 Wq, 4 bq, 5 gq, 6 beq,
    // 7 Wk, 8 bk, 9 gk, 10 bek, 11 Wv, 12 bv, 13 Wm1, 14 bm1, 15 gm, 16 bem,
    // 17 Wm2, 18 bm2, 19 Wp1, 20 bp1, 21 gp, 22 bep, 23 Wp2, 24 bp2,
    // 25 Ww1, 26 bw1, 27 gw, 28 bew, 29 Ww2, 30 bw2
    const float* feat = (const float*)d_in[0];
    const float* Wv   = (const float*)d_in[11];
    const float* bv   = (const float*)d_in[12];
    float* out = (float*)d_out;

    dim3 grid(NROWS / 16);   // 128 blocks, 16 rows each
    dim3 block(256);
    value_gemm_kernel<<<grid, block, 0, stream>>>(feat, Wv, bv, out);
}

// Round 2
// 11.574 us; speedup vs baseline: 1.2502x; 1.2502x over previous
//
#include <hip/hip_runtime.h>

// Reference collapses: softmax over axis=-2 sums to 1, and value[i,k] is
// independent of that axis, so out = feat @ Wv.T + bv exactly.
// This is a tiny latency-bound GEMM (2048x128 @ 128x128): maximize
// parallelism (1024 blocks), minimize per-block staging (16 KB k-tile).

#define NROWS 2048
#define DIM 128
#define KT 32   // output columns per block
#define RT 8    // rows per block

__global__ __launch_bounds__(256) void value_gemm_kernel(
    const float* __restrict__ feat,   // [2048,128]
    const float* __restrict__ Wv,     // [128,128] (out = feat @ Wv^T)
    const float* __restrict__ bv,     // [128]
    float* __restrict__ out)          // [2048,128]
{
    // Wv k-tile staged as float4 granules, XOR-swizzled: granule d4 of row k
    // stored at slot d4^k. Read phase: 32 lanes (k=0..31) at same d4 hit 32
    // distinct slots -> conflict-free. 16 KiB.
    __shared__ float wlds[KT * DIM];

    const int t = threadIdx.x;
    const int row0 = blockIdx.x * RT;
    const int k0 = blockIdx.y * KT;

    const float4* wv4 = (const float4*)(Wv + k0 * DIM);
    float4* wl4 = (float4*)wlds;

    // Stage: KT*32 = 1024 granules, 4 per thread, coalesced global reads.
#pragma unroll
    for (int i = 0; i < 4; ++i) {
        int m = t + i * 256;          // 0..1023
        int k = m >> 5;               // local k row 0..31
        int d4 = m & 31;              // granule 0..31
        wl4[(k << 5) | (d4 ^ k)] = wv4[m];
    }
    __syncthreads();

    const int k = t & 31;             // local output column
    const int g = t >> 5;             // row group 0..7 -> one row per thread
    const int r = row0 + g;

    float acc = bv[k0 + k];
    const float4* f4 = (const float4*)(feat + r * DIM);

#pragma unroll
    for (int d4 = 0; d4 < 32; ++d4) {
        float4 w = wl4[(k << 5) | (d4 ^ k)];
        float4 f = f4[d4];            // uniform per 32-lane group: broadcast
        acc += f.x * w.x + f.y * w.y + f.z * w.z + f.w * w.w;
    }

    out[r * DIM + k0 + k] = acc;      // lanes k contiguous: coalesced 128B
}

extern "C" void kernel_launch(void* const* d_in, const int* in_sizes, int n_in,
                              void* d_out, int out_size, void* d_ws, size_t ws_size,
                              hipStream_t stream) {
    // setup_inputs order: 0 feat, 1 bias, 2 mul, 3 Wq, 4 bq, 5 gq, 6 beq,
    // 7 Wk, 8 bk, 9 gk, 10 bek, 11 Wv, 12 bv, 13 Wm1, 14 bm1, 15 gm, 16 bem,
    // 17 Wm2, 18 bm2, 19 Wp1, 20 bp1, 21 gp, 22 bep, 23 Wp2, 24 bp2,
    // 25 Ww1, 26 bw1, 27 gw, 28 bew, 29 Ww2, 30 bw2
    const float* feat = (const float*)d_in[0];
    const float* Wv   = (const float*)d_in[11];
    const float* bv   = (const float*)d_in[12];
    float* out = (float*)d_out;

    dim3 grid(NROWS / RT, DIM / KT);  // 256 x 4 = 1024 blocks
    dim3 block(256);
    value_gemm_kernel<<<grid, block, 0, stream>>>(feat, Wv, bv, out);
}

// Round 3
// 10.619 us; speedup vs baseline: 1.3627x; 1.0899x over previous
//
#include <hip/hip_runtime.h>

// Reference collapses: softmax over axis=-2 sums to 1 and value[i,k] doesn't
// depend on that axis, so out = feat @ Wv.T + bv exactly.
// Tiny GEMM (2048x128 @ 128x128^T): ~2 MB ideal traffic. Measurement is
// dominated by launch/replay overhead; kernel tuned to be LDS/latency-lean:
//  - J=2 rows per thread amortizes the per-lane Wv LDS stream (134->67 MB)
//  - 1024 blocks x 128 threads, 8 KB LDS -> max occupancy (32 waves/CU)

#define NROWS 2048
#define DIM 128
#define KT 16   // output columns per block
#define RT 16   // rows per block (2 per thread)

__global__ __launch_bounds__(128) void value_gemm_kernel(
    const float* __restrict__ feat,   // [2048,128]
    const float* __restrict__ Wv,     // [128,128] (out = feat @ Wv^T)
    const float* __restrict__ bv,     // [128]
    float* __restrict__ out)          // [2048,128]
{
    // Wv k-tile as float4 granules, XOR-swizzled: granule d4 of row k at
    // slot d4^k (k<16 <= 32 granules: stays in range). Read: 16 lanes at
    // same d4 hit 16 distinct granules (2-way bank quads = free); lane pairs
    // k duplicated across row-groups broadcast. 8 KiB.
    __shared__ float wlds[KT * DIM];

    const int t = threadIdx.x;
    const int row0 = blockIdx.x * RT;
    const int k0 = blockIdx.y * KT;

    const float4* wv4 = (const float4*)(Wv + k0 * DIM);
    float4* wl4 = (float4*)wlds;

    // Stage: KT*32 = 512 granules, 4 per thread, coalesced 2KB bursts.
#pragma unroll
    for (int i = 0; i < 4; ++i) {
        int m = t + i * 128;          // 0..511
        int k = m >> 5;               // local k row 0..15
        int d4 = m & 31;              // granule 0..31
        wl4[(k << 5) | (d4 ^ k)] = wv4[m];
    }
    __syncthreads();

    const int k = t & 15;             // local output column
    const int g = t >> 4;             // row group 0..7
    const int r0 = row0 + g;          // this thread's two rows
    const int r1 = row0 + g + 8;

    const float bk = bv[k0 + k];
    float acc0 = bk, acc1 = bk;

    const float4* fa = (const float4*)(feat + r0 * DIM);
    const float4* fb = (const float4*)(feat + r1 * DIM);

#pragma unroll 8
    for (int d4 = 0; d4 < 32; ++d4) {
        float4 w = wl4[(k << 5) | (d4 ^ k)];
        float4 a = fa[d4];            // uniform per 16-lane group: broadcast
        float4 b = fb[d4];
        acc0 += a.x * w.x + a.y * w.y + a.z * w.z + a.w * w.w;
        acc1 += b.x * w.x + b.y * w.y + b.z * w.z + b.w * w.w;
    }

    out[r0 * DIM + k0 + k] = acc0;    // 16 lanes contiguous: 64B bursts
    out[r1 * DIM + k0 + k] = acc1;
}

extern "C" void kernel_launch(void* const* d_in, const int* in_sizes, int n_in,
                              void* d_out, int out_size, void* d_ws, size_t ws_size,
                              hipStream_t stream) {
    // setup_inputs order: 0 feat, 1 bias, 2 mul, 3 Wq, 4 bq, 5 gq, 6 beq,
    // 7 Wk, 8 bk, 9 gk, 10 bek, 11 Wv, 12 bv, 13 Wm1, 14 bm1, 15 gm, 16 bem,
    // 17 Wm2, 18 bm2, 19 Wp1, 20 bp1, 21 gp, 22 bep, 23 Wp2, 24 bp2,
    // 25 Ww1, 26 bw1, 27 gw, 28 bew, 29 Ww2, 30 bw2
    const float* feat = (const float*)d_in[0];
    const float* Wv   = (const float*)d_in[11];
    const float* bv   = (const float*)d_in[12];
    float* out = (float*)d_out;

    dim3 grid(NROWS / RT, DIM / KT);  // 128 x 8 = 1024 blocks
    dim3 block(128);
    value_gemm_kernel<<<grid, block, 0, stream>>>(feat, Wv, bv, out);
}